// Round 8
// baseline (309.829 us; speedup 1.0000x reference)
//
#include <hip/hip_runtime.h>
#include <float.h>

// SearchTransfer MI355X — R18: B-resident persistent-column GEMM blocks.
// Model (validated R10/R16): chunk wall ~ 127-156 cyc/DMA-instr + ~800.
// Each block now owns (b, cb) and TWO row-tiles: B tile (256 rows x 160 k')
// staged ONCE into resident 80KB LDS (streamed one-ahead during rt0's
// chunks), A double-buffered 2x16KB. DMA instrs: rt0 32/chunk (=R16),
// rt1 16/chunk; staged bytes 415->311 MB. LDS 124KB (+12KB dedicated
// epilogue scratch so B survives). Sync skeleton = R10 (1 barrier/chunk,
// depth-1 prefetch). pv bit-identical (same accum order/swizzle/ties).
// k_pack2/k_merge/k_fix/k_fold unchanged from R17 (controls).
// B=2, C=16, H=W=96, k=3,pad=1,stride=1, lv=2. L=9216, KF=144.
// out = [T_org (2*16*192*192 f32), S (2*9216 as f32)]

#define BATCH 2
#define CCH   16
#define HH    96
#define WW    96
#define LP    9216
#define KF    144
#define K3    160      // 5 chunks x 32 k' (hi f16 only; k'>=144 zero-pad)
#define OH    192
#define OW    192
#define NRT2  36       // row tiles of 256
#define NCB2  36       // col blocks of 256

typedef _Float16 f16;
typedef __attribute__((ext_vector_type(8))) _Float16 f16x8;
typedef __attribute__((ext_vector_type(4))) float    f32x4;

__device__ __forceinline__ void async16(const void* g, void* l) {
    __builtin_amdgcn_global_load_lds(
        (const __attribute__((address_space(1))) void*)g,
        (__attribute__((address_space(3))) void*)l, 16, 0, 0);
}

// ---------------------------------------------------- fused norm + pack ----
// UNCHANGED from R17 (parallel norm). hi f16 only. Norms exact fp32.
__global__ __launch_bounds__(256) void k_pack2(
        const float* __restrict__ ref, const float* __restrict__ lr,
        float* __restrict__ rinv, float* __restrict__ bns,
        f16* __restrict__ Abig, f16* __restrict__ Bbig) {
    __shared__ float imgS[CCH][3][26];   // x origin at global xi = q*24-1
    __shared__ float pnorm[24][8];
    __shared__ float scl[24];
    int py = blockIdx.x, b = blockIdx.y;
    int side = blockIdx.z >> 2, q = blockIdx.z & 3;
    int tid = threadIdx.x;
    const float* img = (side ? lr : ref) + (size_t)b * CCH * HH * WW;

    for (int i = tid; i < CCH * 3 * 26; i += 256) {
        int c = i / 78, rem = i - c * 78;
        int rr = rem / 26, xx = rem - rr * 26;
        int y = py + rr - 1, xi = q * 24 - 1 + xx;
        float v = 0.f;
        if ((unsigned)y < (unsigned)HH && (unsigned)xi < (unsigned)WW)
            v = img[(c * HH + y) * WW + xi];
        imgS[c][rr][xx] = v;
    }
    __syncthreads();

    if (tid < 192) {                     // N1: partial norms
        int pxl = tid >> 3, part = tid & 7;
        float s = 0.f;
        #pragma unroll
        for (int cc = 0; cc < 2; ++cc) {
            int c = part * 2 + cc;
            #pragma unroll
            for (int dy = 0; dy < 3; ++dy)
                #pragma unroll
                for (int dx = 0; dx < 3; ++dx) {
                    float v = imgS[c][dy][pxl + dx];   // 0 when OOB: exact
                    s += v * v;
                }
        }
        pnorm[pxl][part] = s;
    }
    __syncthreads();

    if (tid < 24) {                      // N2: deterministic reduce
        int pxl = tid;
        float s = 0.f;
        #pragma unroll
        for (int p = 0; p < 8; ++p) s += pnorm[pxl][p];
        int gl = b * LP + py * 96 + q * 24 + pxl;
        if (side) { bns[gl] = 1024.0f * sqrtf(s); scl[pxl] = 1024.0f; }
        else { float r = 1.0f / fmaxf(sqrtf(s), 1e-12f); rinv[gl] = r; scl[pxl] = 1024.0f * r; }
    }
    __syncthreads();

    f16* dstb = (side ? Bbig : Abig) + (size_t)(b * LP + py * 96 + q * 24) * K3;
    for (int i = tid; i < 24 * 20; i += 256) {          // 20 granules/row
        int pxl = i / 20, g = i - pxl * 20;
        int f0 = g * 8;
        float sc = scl[pxl];
        f16x8 o;
        #pragma unroll
        for (int e = 0; e < 8; ++e) {
            int f = f0 + e;                             // 0..159 (>=144 pad)
            float v = 0.f;
            if (f < KF) {
                int c = f / 9, r9 = f - c * 9;
                int dy = r9 / 3, dx = r9 - dy * 3;
                v = imgS[c][dy][pxl + dx] * sc;
            }
            o[e] = (f16)v;
        }
        *(f16x8*)(dstb + (size_t)pxl * K3 + g * 8) = o;
    }
}

// -------------------------------------------------- MFMA GEMM + top-2 ------
// R18: persistent (b, cb, rg) block, rt = rg*2 + {0,1}. B resident in bsm
// (5 chunks x 16KB), A dbuf in smem (2 x 16KB), scratch dedicated 12KB.
// rt0 chunks stage {A[rt0][ch+1], B[ch+1]}; rt1 chunks stage A only; the
// A[rt1][0] prefetch is issued during rt0's last chunk. 1 barrier/chunk.
__global__ __launch_bounds__(1024) void k_mfma(
        const f16* __restrict__ Abig, const f16* __restrict__ Bbig,
        float* __restrict__ pv1, int* __restrict__ pi1, float* __restrict__ pv2) {
    __shared__ f16 smem[2][8192];      // A dbuf: 256 rows x 64 B per buffer
    __shared__ f16 bsm[5][8192];       // B resident: 5 chunks x 256 rows x 64 B
    __shared__ float scr[3072];        // epilogue scratch (sv1/si1/sv2 [4][256])
    int tid = threadIdx.x, lane = tid & 63, w = tid >> 6;   // w: 0..15
    int wm = w & 3, wn = w >> 2;
    int l15 = lane & 15, quad = lane >> 4;

    int bid = blockIdx.x;              // 0..1295
    int rg = bid % 18;
    int cb = (bid / 18) % 36;
    int b  = bid / 648;
    int c0 = cb * 256;

    // DMA lane mapping (16 rows per instr, 2 rows per 128-B line, granule
    // XOR swizzle): row-in-group ri, source granule qsw (self-inverse).
    int ri  = ((lane >> 3) << 1) | ((lane >> 2) & 1);
    int qsw = (lane & 3) ^ ((lane >> 3) & 3);
    // wave w stages rows [16w, 16w+16) of each 256-row tile; dest w*1024.
    const f16* bsrc = Bbig + (size_t)(b * LP + c0 + w * 16 + ri) * K3 + qsw * 8;
    int ldsoff = w * 1024;

    // ds_read byte offsets (row r -> line r>>1, half r&1, granule quad^(line&3))
    int l2 = l15 >> 1, lo1 = l15 & 1;
    int gsel = (quad ^ (l2 & 3)) * 16;
    int abyte[4], bbyte[4];
    #pragma unroll
    for (int t = 0; t < 4; ++t) {
        abyte[t] = (wm * 32 + t * 8 + l2) * 128 + lo1 * 64 + gsel;
        bbyte[t] = (wn * 32 + t * 8 + l2) * 128 + lo1 * 64 + gsel;
    }

    // prologue: A[rt0][0] -> smem[0], B[0] -> bsm[0]
    const f16* asrc0 = Abig + (size_t)(b * LP + rg * 512 + w * 16 + ri) * K3 + qsw * 8;
    async16(asrc0, (char*)smem[0] + ldsoff);
    async16(bsrc, (char*)bsm[0] + ldsoff);

    for (int rt2 = 0; rt2 < 2; ++rt2) {
        int rt = rg * 2 + rt2;
        int r0 = rt * 256;
        const f16* asrc = asrc0 + (size_t)rt2 * 256 * K3;

        f32x4 acc[4][4];
        #pragma unroll
        for (int ii = 0; ii < 4; ++ii)
            #pragma unroll
            for (int j = 0; j < 4; ++j) { acc[ii][j][0]=0.f; acc[ii][j][1]=0.f; acc[ii][j][2]=0.f; acc[ii][j][3]=0.f; }

        for (int ch = 0; ch < 5; ++ch) {
            int g = rt2 * 5 + ch;      // global chunk counter; buf = g&1
            __syncthreads();           // drains own DMA; smem[g&1], bsm[ch] ready
            if (ch < 4) {
                async16(asrc + (ch + 1) * 32, (char*)smem[(g + 1) & 1] + ldsoff);
                if (rt2 == 0)
                    async16(bsrc + (ch + 1) * 32, (char*)bsm[ch + 1] + ldsoff);
            } else if (rt2 == 0) {     // prefetch A[rt1][0] during rt0 ch4
                async16(asrc + 256 * K3, (char*)smem[(g + 1) & 1] + ldsoff);
            }
            const char* abuf = (const char*)smem[g & 1];
            const char* bbuf = (const char*)bsm[ch];
            f16x8 af[4], bf[4];
            #pragma unroll
            for (int t = 0; t < 4; ++t) af[t] = *(const f16x8*)(abuf + abyte[t]);
            #pragma unroll
            for (int t = 0; t < 4; ++t) bf[t] = *(const f16x8*)(bbuf + bbyte[t]);
            #pragma unroll
            for (int rtt = 0; rtt < 4; ++rtt)
                #pragma unroll
                for (int ct = 0; ct < 4; ++ct)
                    acc[rtt][ct] = __builtin_amdgcn_mfma_f32_16x16x32_f16(af[rtt], bf[ct], acc[rtt][ct], 0, 0, 0);
        }
        __syncthreads();               // all reads of this rt done

        float* sv1 = scr;                              // [4][256]
        int*   si1 = (int*)(scr + 1024);
        float* sv2 = scr + 2048;

        int rbase = r0 + wm * 64 + (quad << 2);
        #pragma unroll
        for (int ct = 0; ct < 4; ++ct) {
            float v1 = -FLT_MAX, v2 = -FLT_MAX; int i1 = 0;
            #pragma unroll
            for (int rtt = 0; rtt < 4; ++rtt)
                #pragma unroll
                for (int e = 0; e < 4; ++e) {          // ascending rows; strict > = first wins
                    float v = acc[rtt][ct][e];
                    int rg2 = rbase + rtt * 16 + e;
                    if (v > v1) { v2 = v1; v1 = v; i1 = rg2; }
                    else if (v > v2) v2 = v;
                }
            #pragma unroll
            for (int off = 16; off < 64; off <<= 1) {  // reduce over quad (rows)
                float ov1 = __shfl_xor(v1, off, 64);
                int   oi1 = __shfl_xor(i1, off, 64);
                float ov2 = __shfl_xor(v2, off, 64);
                if (ov1 > v1 || (ov1 == v1 && oi1 < i1)) { v2 = fmaxf(v1, ov2); v1 = ov1; i1 = oi1; }
                else v2 = fmaxf(v2, ov1);
            }
            if (quad == 0) {
                int col = wn * 64 + ct * 16 + l15;
                sv1[wm * 256 + col] = v1; si1[wm * 256 + col] = i1; sv2[wm * 256 + col] = v2;
            }
        }
        __syncthreads();
        if (tid < 256) {
            int col = tid;
            float v1 = sv1[col]; int i1 = si1[col]; float v2 = sv2[col];
            #pragma unroll
            for (int m = 1; m < 4; ++m) {              // ascending wm = ascending rows
                float ov1 = sv1[m * 256 + col]; int oi1 = si1[m * 256 + col]; float ov2 = sv2[m * 256 + col];
                if (ov1 > v1) { v2 = fmaxf(v1, ov2); v1 = ov1; i1 = oi1; }
                else v2 = fmaxf(v2, ov1);
            }
            size_t o = ((size_t)(b * NRT2 + rt)) * LP + c0 + col;
            pv1[o] = v1; pi1[o] = i1; pv2[o] = v2;
        }
    }
}

// --------------------------------------------------------- merge kernel ----
// UNCHANGED from R16. Coalesced col-parallel merge; compact flag list.
__global__ __launch_bounds__(256) void k_merge(
        const float* __restrict__ pv1, const int* __restrict__ pi1,
        const float* __restrict__ pv2, const float* __restrict__ bns,
        int* __restrict__ Sint, float* __restrict__ Sout,
        int* __restrict__ flaglist, int* __restrict__ nflag) {
    int b = blockIdx.y;
    int col = blockIdx.x * 256 + threadIdx.x;
    int gid = b * LP + col;
    float v1 = -FLT_MAX, v2 = -FLT_MAX; int i1 = 0;
    for (int rc = 0; rc < NRT2; ++rc) {                // ascending: first-wins
        size_t o = ((size_t)(b * NRT2 + rc)) * LP + col;
        float cv1 = pv1[o]; int ci1 = pi1[o]; float cv2 = pv2[o];
        if (cv1 > v1) { v2 = fmaxf(v1, cv2); v1 = cv1; i1 = ci1; }
        else v2 = fmaxf(v2, cv1);
    }
    Sint[gid] = i1;
    Sout[gid] = (float)i1;
    float tau = bns[gid] * 0.5f;                       // tau' = 0.5*bns
    if (v1 - v2 < tau) {
        int k = atomicAdd(nflag, 1);
        flaglist[k] = gid;
    }
}

// ----------------------------------------------------------- fix kernel ----
// UNCHANGED from R16. Grid-stride over flag list; exact fp32 argmax.
__global__ __launch_bounds__(256) void k_fix(
        const float* __restrict__ refimg, const float* __restrict__ lrimg,
        const float* __restrict__ rinv, const float* __restrict__ pv1,
        const float* __restrict__ bns,
        const int* __restrict__ flaglist, const int* __restrict__ nflag,
        int* __restrict__ Sint, float* __restrict__ Sout) {
    __shared__ float bcol[KF];
    __shared__ float spv[NRT2];
    __shared__ float red[4]; __shared__ int redi[4];
    int tid = threadIdx.x;
    int nf = *nflag;
    for (int fi = blockIdx.x; fi < nf; fi += gridDim.x) {
        int gid = flaglist[fi];
        int b = gid / LP, col = gid - b * LP;
        int lh = col / 96, lw = col - lh * 96;
        __syncthreads();                               // protect bcol/spv reuse
        if (tid < KF) {
            int c = tid / 9, r = tid - c * 9;
            int dy = r / 3, dx = r - dy * 3;
            int y = lh + dy - 1, x = lw + dx - 1;
            float v = 0.f;
            if ((unsigned)y < (unsigned)HH && (unsigned)x < (unsigned)WW)
                v = lrimg[((size_t)(b * CCH + c) * HH + y) * WW + x];
            bcol[tid] = v;
        }
        if (tid < NRT2) spv[tid] = pv1[((size_t)(b * NRT2 + tid)) * LP + col];
        __syncthreads();
        float v1 = -FLT_MAX;
        for (int rc = 0; rc < NRT2; ++rc) v1 = fmaxf(v1, spv[rc]);
        float thresh = v1 - bns[gid] * 0.5f;           // same tau' margin
        float best = -FLT_MAX; int bi = 0x7fffffff;
        for (int rc = 0; rc < NRT2; ++rc) {            // ascending rows
            if (spv[rc] < thresh) continue;            // prune (uniform)
            int row = rc * 256 + tid;
            int py = row / WW, px = row - py * WW;
            float s = 0.f;
            for (int c = 0; c < CCH; ++c) {
                const float* ic = refimg + (size_t)(b * CCH + c) * HH * WW;
                #pragma unroll
                for (int dy = 0; dy < 3; ++dy) {
                    int y = py + dy - 1;
                    if ((unsigned)y >= (unsigned)HH) continue;
                    #pragma unroll
                    for (int dx = 0; dx < 3; ++dx) {
                        int x = px + dx - 1;
                        if ((unsigned)x >= (unsigned)WW) continue;
                        s = fmaf(ic[y * WW + x], bcol[c * 9 + dy * 3 + dx], s);
                    }
                }
            }
            s *= rinv[b * LP + row];
            if (s > best || (s == best && row < bi)) { best = s; bi = row; }
        }
        #pragma unroll
        for (int off = 1; off < 64; off <<= 1) {
            float ov = __shfl_xor(best, off, 64);
            int   oi = __shfl_xor(bi, off, 64);
            if (ov > best || (ov == best && oi < bi)) { best = ov; bi = oi; }
        }
        if ((tid & 63) == 0) { red[tid >> 6] = best; redi[tid >> 6] = bi; }
        __syncthreads();
        if (tid == 0) {
            float b0 = red[0]; int i0 = redi[0];
            for (int k = 1; k < 4; ++k)
                if (red[k] > b0 || (red[k] == b0 && redi[k] < i0)) { b0 = red[k]; i0 = redi[k]; }
            Sint[gid] = i0;
            Sout[gid] = (float)i0;
        }
    }
}

// ---------------------------------------------------------- fold kernel ----
// UNCHANGED from R17 (wave-uniform patch loop).
__global__ __launch_bounds__(256) void k_fold(
        const int* __restrict__ Sint, const float* __restrict__ org,
        float* __restrict__ outT) {
    __shared__ int s_S[6][6];
    int tx = blockIdx.x, ty = blockIdx.y, b = blockIdx.z;
    int x0 = tx * 8, y0 = ty * 8;
    int lhb = 4 * ty - 1; if (lhb < 0) lhb = 0;
    int lwb = 4 * tx - 1; if (lwb < 0) lwb = 0;
    int lhe = 4 * ty + 4; if (lhe > 95) lhe = 95;
    int lwe = 4 * tx + 4; if (lwe > 95) lwe = 95;
    int nh = lhe - lhb + 1, nw = lwe - lwb + 1;        // 5 or 6
    int tid = threadIdx.x;

    if (tid < 36) {
        int ph = tid / 6, pw = tid - ph * 6;
        int lh = lhb + ph, lw = lwb + pw;
        s_S[ph][pw] = (lh <= lhe && lw <= lwe) ? Sint[b * LP + lh * 96 + lw] : 0;
    }
    __syncthreads();

    int wid = tid >> 6, pix = tid & 63;
    int pyL = pix >> 3, pxL = pix & 7;
    int y = y0 + pyL, x = x0 + pxL;
    const float* orgb = org + ((size_t)b * CCH + wid * 4) * OH * OW;
    float acc[4];
    #pragma unroll
    for (int c = 0; c < 4; ++c) acc[c] = 0.f;
    for (int ph = 0; ph < nh; ++ph) {                  // wave-uniform loop
        int lh = lhb + ph;
        int dy = y + 2 - 2 * lh;                       // per lane
        for (int pw = 0; pw < nw; ++pw) {
            int lw = lwb + pw;
            int dx = x + 2 - 2 * lw;
            int s  = s_S[ph][pw];                      // uniform -> broadcast
            int sh = s / 96, sw = s - sh * 96;
            if ((unsigned)dy < 6u && (unsigned)dx < 6u) {
                int u = 2 * sh + dy - 2;
                int v = 2 * sw + dx - 2;
                if ((unsigned)u < (unsigned)OH && (unsigned)v < (unsigned)OW) {
                    const float* p = orgb + u * OW + v;
                    #pragma unroll
                    for (int c = 0; c < 4; ++c) acc[c] += p[(size_t)c * OH * OW];
                }
            }
        }
    }
    #pragma unroll
    for (int c = 0; c < 4; ++c)
        outT[(((size_t)(b * CCH + wid * 4 + c)) * OH + y) * OW + x] = acc[c];
}

// --------------------------------------------------------------- launch ----
extern "C" void kernel_launch(void* const* d_in, const int* in_sizes, int n_in,
                              void* d_out, int out_size, void* d_ws, size_t ws_size,
                              hipStream_t stream) {
    const float* lrsr  = (const float*)d_in[0];
    const float* refsr = (const float*)d_in[1];
    const float* org   = (const float*)d_in[2];

    char* ws = (char*)d_ws;
    size_t o = 0;
    float* rinv     = (float*)(ws + o); o += (size_t)BATCH * LP * 4;
    float* bns      = (float*)(ws + o); o += (size_t)BATCH * LP * 4;
    float* pv1      = (float*)(ws + o); o += (size_t)BATCH * NRT2 * LP * 4;
    int*   pi1      = (int*)  (ws + o); o += (size_t)BATCH * NRT2 * LP * 4;
    float* pv2      = (float*)(ws + o); o += (size_t)BATCH * NRT2 * LP * 4;
    f16*   Abig     = (f16*)  (ws + o); o += (size_t)BATCH * LP * K3 * 2;
    f16*   Bbig     = (f16*)  (ws + o); o += (size_t)BATCH * LP * K3 * 2;
    int*   Sint     = (int*)  (ws + o); o += (size_t)BATCH * LP * 4;
    int*   flaglist = (int*)  (ws + o); o += (size_t)BATCH * LP * 4;
    int*   nflag    = (int*)  (ws + o); o += 16;

    float* outT = (float*)d_out;                          // 2*16*192*192
    float* outS = outT + (size_t)BATCH * CCH * OH * OW;   // 2*9216 as f32

    hipMemsetAsync(nflag, 0, 4, stream);
    k_pack2<<<dim3(96, BATCH, 8), 256, 0, stream>>>(refsr, lrsr, rinv, bns, Abig, Bbig);
    k_mfma<<<dim3(1296), 1024, 0, stream>>>(Abig, Bbig, pv1, pi1, pv2);
    k_merge<<<dim3(LP / 256, BATCH), 256, 0, stream>>>(pv1, pi1, pv2, bns,
                                                       Sint, outS, flaglist, nflag);
    k_fix<<<dim3(768), 256, 0, stream>>>(refsr, lrsr, rinv, pv1, bns,
                                         flaglist, nflag, Sint, outS);
    k_fold<<<dim3(24, 24, BATCH), 256, 0, stream>>>(Sint, org, outT);
}